// Round 1
// baseline (464.499 us; speedup 1.0000x reference)
//
#include <hip/hip_runtime.h>
#include <cstdint>
#include <cstddef>

#define B_ROWS 8192
#define OUT_N  1024
#define EXC_IN 4096
#define INH_IN 2048
#define K_EXC  32
#define K_INH  16
#define TILE_N 4

// ---------------------------------------------------------------------------
// Kernel 1: per-row top-K of pre_w -> compressed (val = exp(pre_w), idx).
// Tie-break: lowest index wins (matches jax.lax.top_k / stable argsort).
// Key = (monotone_u32(float) << 12) | (4095 - idx)  -> u64 argmax.
// ---------------------------------------------------------------------------
template<int COLS, int K>
__global__ __launch_bounds__(256) void topk_kernel(const float* __restrict__ pre_w,
                                                   float2* __restrict__ out_w)
{
    const int row  = blockIdx.x;
    const int tid  = threadIdx.x;
    const int lane = tid & 63;
    const int wave = tid >> 6;
    constexpr int ELEMS = COLS / 256;

    __shared__ unsigned long long red[5];

    const float* src = pre_w + (size_t)row * COLS;
    unsigned long long keys[ELEMS];
#pragma unroll
    for (int i = 0; i < ELEMS; ++i) {
        const int idx = tid + i * 256;                    // coalesced
        unsigned int u = __float_as_uint(src[idx]);
        unsigned int m = (u >> 31) ? ~u : (u | 0x80000000u);   // monotone map
        keys[i] = ((unsigned long long)m << 12) | (unsigned long long)(4095 - idx);
    }

#pragma unroll 1
    for (int r = 0; r < K; ++r) {
        // local max
        unsigned long long best = 0ull;
#pragma unroll
        for (int i = 0; i < ELEMS; ++i) best = (keys[i] > best) ? keys[i] : best;
        // wave butterfly max (64 lanes)
#pragma unroll
        for (int m = 32; m > 0; m >>= 1) {
            unsigned long long o = __shfl_xor(best, m, 64);
            best = (o > best) ? o : best;
        }
        if (lane == 0) red[wave] = best;
        __syncthreads();
        if (tid == 0) {
            unsigned long long b = red[0];
            b = (red[1] > b) ? red[1] : b;
            b = (red[2] > b) ? red[2] : b;
            b = (red[3] > b) ? red[3] : b;
            red[4] = b;
        }
        __syncthreads();
        const unsigned long long win = red[4];

        if (tid == 0) {
            const unsigned int idx = 4095u - (unsigned int)(win & 0xFFFull);
            const unsigned int m   = (unsigned int)(win >> 12);
            const unsigned int u   = (m >> 31) ? (m & 0x7FFFFFFFu) : ~m;
            const float v = __uint_as_float(u);
            out_w[(size_t)row * K + r] = make_float2(expf(v), __uint_as_float(idx));
        }
        // branch-free clear of the winner (keys are unique; only owner matches)
#pragma unroll
        for (int i = 0; i < ELEMS; ++i) keys[i] = (keys[i] == win) ? 0ull : keys[i];
    }
}

// ---------------------------------------------------------------------------
// Kernel 2: fused sparse exc/inh gather + branch contraction + reactivation.
// Block: 256 threads, TILE_N=4 batch rows, all 1024 outputs.
// LDS: 64 KB, staged with x rows then reused for inh rows.
// ---------------------------------------------------------------------------
__global__ __launch_bounds__(256, 2) void dendritic_main_kernel(
    const float*  __restrict__ x,
    const float*  __restrict__ inh,
    const float4* __restrict__ branch,   // [B][1024] float4
    const float2* __restrict__ wexc,     // [1024][32] (val, idx-bits)
    const float2* __restrict__ winh,     // [1024][16]
    const float4* __restrict__ wblock,   // [1024]
    const float*  __restrict__ presig,   // [1024]
    const float*  __restrict__ logalpha, // [1024]
    float*        __restrict__ out)      // [B][1024]
{
    __shared__ float sx[TILE_N * EXC_IN];   // 64 KB

    const int tid = threadIdx.x;
    const int n0  = blockIdx.x * TILE_N;

    // ---- stage x tile (row-major), coalesced float4 ----
    {
        const float4* xs  = (const float4*)(x + (size_t)n0 * EXC_IN);
        float4*       sx4 = (float4*)sx;
#pragma unroll
        for (int i = 0; i < (TILE_N * EXC_IN / 4) / 256; ++i)
            sx4[tid + i * 256] = xs[tid + i * 256];
    }
    __syncthreads();

    // ---- excitation gather-accumulate ----
    float acc_e[4][TILE_N];
#pragma unroll
    for (int j = 0; j < 4; ++j)
#pragma unroll
        for (int n = 0; n < TILE_N; ++n) acc_e[j][n] = 0.f;

#pragma unroll
    for (int j = 0; j < 4; ++j) {
        const int o = tid + j * 256;
        const float2* wr = wexc + (size_t)o * K_EXC;
#pragma unroll 4
        for (int k = 0; k < K_EXC; ++k) {
            const float2 wv = wr[k];
            const int c = (int)__float_as_uint(wv.y);
            const float* p = sx + c;
#pragma unroll
            for (int n = 0; n < TILE_N; ++n)
                acc_e[j][n] = fmaf(p[n * EXC_IN], wv.x, acc_e[j][n]);
        }
    }
    __syncthreads();

    // ---- restage LDS with inh tile ----
    {
        const float4* is4 = (const float4*)(inh + (size_t)n0 * INH_IN);
        float4*       sx4 = (float4*)sx;
#pragma unroll
        for (int i = 0; i < (TILE_N * INH_IN / 4) / 256; ++i)
            sx4[tid + i * 256] = is4[tid + i * 256];
    }
    __syncthreads();

    // ---- inhibition gather-accumulate ----
    float acc_i[4][TILE_N];
#pragma unroll
    for (int j = 0; j < 4; ++j)
#pragma unroll
        for (int n = 0; n < TILE_N; ++n) acc_i[j][n] = 0.f;

#pragma unroll
    for (int j = 0; j < 4; ++j) {
        const int o = tid + j * 256;
        const float2* wr = winh + (size_t)o * K_INH;
#pragma unroll 4
        for (int k = 0; k < K_INH; ++k) {
            const float2 wv = wr[k];
            const int c = (int)__float_as_uint(wv.y);
            const float* p = sx + c;
#pragma unroll
            for (int n = 0; n < TILE_N; ++n)
                acc_i[j][n] = fmaf(p[n * INH_IN], wv.x, acc_i[j][n]);
        }
    }

    // ---- branch contraction + voltage + reactivation, streamed ----
#pragma unroll
    for (int j = 0; j < 4; ++j) {
        const int o = tid + j * 256;
        const float4 wb = wblock[o];
        const float cond  = wb.x + wb.y + wb.z + wb.w;
        const float Vth   = 1.f / (1.f + expf(-presig[o]));
        const float alpha = expf(logalpha[o]);
#pragma unroll
        for (int n = 0; n < TILE_N; ++n) {
            const float4 br = branch[(size_t)(n0 + n) * 1024 + o];
            const float cur = br.x * wb.x + br.y * wb.y + br.z * wb.z + br.w * wb.w;
            const float e  = acc_e[j][n];
            const float ii = acc_i[j][n];
            const float num = e + cur;
            const float den = e + 1.f + cond + ii;
            const float v   = num / den;
            const float d   = v - Vth;
            const float r   = alpha * d * d;
            out[(size_t)(n0 + n) * OUT_N + o] = (d < 0.f) ? 0.f : r;
        }
    }
}

// ---------------------------------------------------------------------------
extern "C" void kernel_launch(void* const* d_in, const int* in_sizes, int n_in,
                              void* d_out, int out_size, void* d_ws, size_t ws_size,
                              hipStream_t stream)
{
    const float* x      = (const float*)d_in[0];
    const float* inh    = (const float*)d_in[1];
    const float* branch = (const float*)d_in[2];
    const float* pwe    = (const float*)d_in[3];
    const float* pwi    = (const float*)d_in[4];
    const float* wb     = (const float*)d_in[5];
    const float* ps     = (const float*)d_in[6];
    const float* la     = (const float*)d_in[7];
    float* out = (float*)d_out;

    // workspace: [1024][32] float2 exc weights, then [1024][16] float2 inh weights
    float2* wexc = (float2*)d_ws;
    float2* winh = (float2*)((char*)d_ws + (size_t)OUT_N * K_EXC * sizeof(float2));

    topk_kernel<EXC_IN, K_EXC><<<OUT_N, 256, 0, stream>>>(pwe, wexc);
    topk_kernel<INH_IN, K_INH><<<OUT_N, 256, 0, stream>>>(pwi, winh);

    dendritic_main_kernel<<<B_ROWS / TILE_N, 256, 0, stream>>>(
        x, inh, (const float4*)branch, wexc, winh,
        (const float4*)wb, ps, la, out);
}

// Round 3
// 457.474 us; speedup vs baseline: 1.0154x; 1.0154x over previous
//
#include <hip/hip_runtime.h>
#include <cstdint>
#include <cstddef>

#define B_ROWS 8192
#define OUT_N  1024
#define EXC_IN 4096
#define INH_IN 2048
#define K_EXC  32
#define K_INH  16
#define TILE_N 4

// ---------------------------------------------------------------------------
// Top-K: one wave per row, register-resident keys, shuffle-only reduction.
// Key = (monotone_u32(float) << 12) | (4095 - idx)  -> tie = lowest idx wins.
// ---------------------------------------------------------------------------
template<int COLS, int K>
__device__ __forceinline__ void topk_row(const float* __restrict__ src,
                                         float2* __restrict__ orow, int lane)
{
    constexpr int E4 = COLS / 256;          // float4 iters per lane
    unsigned long long keys[E4 * 4];
#pragma unroll
    for (int i = 0; i < E4; ++i) {
        const float4 v = ((const float4*)src)[i * 64 + lane];
        const float vv[4] = {v.x, v.y, v.z, v.w};
#pragma unroll
        for (int q = 0; q < 4; ++q) {
            const int idx = (i * 64 + lane) * 4 + q;
            const unsigned int u = __float_as_uint(vv[q]);
            const unsigned int m = (u >> 31) ? ~u : (u | 0x80000000u);
            keys[i * 4 + q] = ((unsigned long long)m << 12)
                            | (unsigned long long)(4095 - idx);
        }
    }

    unsigned long long win = 0xFFFFFFFFFFFFFFFFull;   // matches nothing
#pragma unroll 1
    for (int r = 0; r < K; ++r) {
        unsigned long long best = 0ull;
#pragma unroll
        for (int i = 0; i < E4 * 4; ++i) {
            const unsigned long long k2 = (keys[i] == win) ? 0ull : keys[i];
            keys[i] = k2;
            best = (k2 > best) ? k2 : best;
        }
#pragma unroll
        for (int m = 1; m < 64; m <<= 1) {
            const unsigned long long o = __shfl_xor(best, m, 64);
            best = (o > best) ? o : best;
        }
        win = best;
        if (lane == 0) {
            const unsigned int idx = 4095u - (unsigned int)(win & 0xFFFull);
            const unsigned int mm  = (unsigned int)(win >> 12);
            const unsigned int u   = (mm & 0x80000000u) ? (mm & 0x7FFFFFFFu) : ~mm;
            const float v = __uint_as_float(u);
            orow[r] = make_float2(expf(v), __uint_as_float(idx));
        }
    }
}

__global__ __launch_bounds__(256, 1) void topk_both_kernel(
    const float* __restrict__ pwe, const float* __restrict__ pwi,
    float2* __restrict__ wexc, float2* __restrict__ winh)
{
    const int wid  = (blockIdx.x * 256 + threadIdx.x) >> 6;   // global wave id
    const int lane = threadIdx.x & 63;
    if (wid < OUT_N) {
        topk_row<EXC_IN, K_EXC>(pwe + (size_t)wid * EXC_IN,
                                wexc + (size_t)wid * K_EXC, lane);
    } else {
        const int r = wid - OUT_N;                            // 0..1023
        topk_row<INH_IN, K_INH>(pwi + (size_t)r * INH_IN,
                                winh + (size_t)r * K_INH, lane);
    }
}

// ---------------------------------------------------------------------------
// 4x4 transpose within lane quads via xor-shuffle butterfly.
// In: lane j (=lane&3) holds x[row j][c0..c0+3]. Out: lane j holds
// x[row 0..3][c0+j] in .x...w.
// ---------------------------------------------------------------------------
__device__ __forceinline__ float4 xpose4(float4 v, int j)
{
    // stage mask=1
    const float u0 = __shfl_xor(v.y, 1, 64), u1 = __shfl_xor(v.x, 1, 64);
    const float u2 = __shfl_xor(v.w, 1, 64), u3 = __shfl_xor(v.z, 1, 64);
    if (j & 1) { v.x = u0; v.z = u2; } else { v.y = u1; v.w = u3; }
    // stage mask=2
    const float w0 = __shfl_xor(v.z, 2, 64), w1 = __shfl_xor(v.w, 2, 64);
    const float w2 = __shfl_xor(v.x, 2, 64), w3 = __shfl_xor(v.y, 2, 64);
    if (j & 2) { v.x = w0; v.y = w1; } else { v.z = w2; v.w = w3; }
    return v;
}

// ---------------------------------------------------------------------------
// Main fused kernel. LDS layout: sx[c][n] with n fast (TILE_N=4) -> each
// gather is ONE ds_read_b128 (4 batch rows). Staging writes are contiguous
// b128 (conflict-free) thanks to the in-register 4x4 transpose.
// ---------------------------------------------------------------------------
__global__ __launch_bounds__(256, 2) void dendritic_main_kernel(
    const float*  __restrict__ x,
    const float*  __restrict__ inh,
    const float4* __restrict__ branch,   // [B][1024] float4
    const float2* __restrict__ wexc,     // [1024][32] (val, idx-bits)
    const float2* __restrict__ winh,     // [1024][16]
    const float4* __restrict__ wblock,   // [1024]
    const float*  __restrict__ presig,   // [1024]
    const float*  __restrict__ logalpha, // [1024]
    float*        __restrict__ out)      // [B][1024]
{
    __shared__ float sx[EXC_IN * TILE_N];   // 64 KB, [c][n] n-fast

    const int tid = threadIdx.x;
    const int n0  = blockIdx.x * TILE_N;
    const int jq  = tid & 3;        // row within quad for staging
    const int c4b = tid >> 2;       // column-quad base for staging

    // ---- stage x tile, transposed ----
#pragma unroll
    for (int it = 0; it < (EXC_IN * TILE_N / 4) / 256; ++it) {   // 16
        const int c4 = c4b + it * 64;
        float4 v = ((const float4*)(x + (size_t)(n0 + jq) * EXC_IN))[c4];
        v = xpose4(v, jq);
        ((float4*)sx)[it * 256 + tid] = v;   // contiguous b128 writes
    }
    __syncthreads();

    // ---- excitation gather (b128) ----
    float acc_e[4][TILE_N];
#pragma unroll
    for (int j = 0; j < 4; ++j)
#pragma unroll
        for (int n = 0; n < TILE_N; ++n) acc_e[j][n] = 0.f;

#pragma unroll
    for (int j = 0; j < 4; ++j) {
        const int o = tid + j * 256;
        const float2* wr = wexc + (size_t)o * K_EXC;
#pragma unroll 8
        for (int k = 0; k < K_EXC; ++k) {
            const float2 wv = wr[k];
            const int c = (int)__float_as_uint(wv.y);
            const float4 xv = ((const float4*)sx)[c];
            acc_e[j][0] = fmaf(xv.x, wv.x, acc_e[j][0]);
            acc_e[j][1] = fmaf(xv.y, wv.x, acc_e[j][1]);
            acc_e[j][2] = fmaf(xv.z, wv.x, acc_e[j][2]);
            acc_e[j][3] = fmaf(xv.w, wv.x, acc_e[j][3]);
        }
    }
    __syncthreads();

    // ---- stage inh tile, transposed ----
#pragma unroll
    for (int it = 0; it < (INH_IN * TILE_N / 4) / 256; ++it) {   // 8
        const int c4 = c4b + it * 64;
        float4 v = ((const float4*)(inh + (size_t)(n0 + jq) * INH_IN))[c4];
        v = xpose4(v, jq);
        ((float4*)sx)[it * 256 + tid] = v;
    }
    __syncthreads();

    // ---- inhibition gather (b128) ----
    float acc_i[4][TILE_N];
#pragma unroll
    for (int j = 0; j < 4; ++j)
#pragma unroll
        for (int n = 0; n < TILE_N; ++n) acc_i[j][n] = 0.f;

#pragma unroll
    for (int j = 0; j < 4; ++j) {
        const int o = tid + j * 256;
        const float2* wr = winh + (size_t)o * K_INH;
#pragma unroll 8
        for (int k = 0; k < K_INH; ++k) {
            const float2 wv = wr[k];
            const int c = (int)__float_as_uint(wv.y);
            const float4 xv = ((const float4*)sx)[c];
            acc_i[j][0] = fmaf(xv.x, wv.x, acc_i[j][0]);
            acc_i[j][1] = fmaf(xv.y, wv.x, acc_i[j][1]);
            acc_i[j][2] = fmaf(xv.z, wv.x, acc_i[j][2]);
            acc_i[j][3] = fmaf(xv.w, wv.x, acc_i[j][3]);
        }
    }

    // ---- branch contraction + voltage + reactivation ----
#pragma unroll
    for (int j = 0; j < 4; ++j) {
        const int o = tid + j * 256;
        const float4 wb = wblock[o];
        const float cond  = wb.x + wb.y + wb.z + wb.w;
        const float Vth   = 1.f / (1.f + expf(-presig[o]));
        const float alpha = expf(logalpha[o]);
#pragma unroll
        for (int n = 0; n < TILE_N; ++n) {
            const float4 br = branch[(size_t)(n0 + n) * OUT_N + o];
            const float cur = br.x * wb.x + br.y * wb.y + br.z * wb.z + br.w * wb.w;
            const float e  = acc_e[j][n];
            const float ii = acc_i[j][n];
            const float num = e + cur;
            const float den = e + 1.f + cond + ii;
            const float v   = num / den;
            const float d   = v - Vth;
            const float r   = alpha * d * d;
            out[(size_t)(n0 + n) * OUT_N + o] = (d < 0.f) ? 0.f : r;
        }
    }
}

// ---------------------------------------------------------------------------
extern "C" void kernel_launch(void* const* d_in, const int* in_sizes, int n_in,
                              void* d_out, int out_size, void* d_ws, size_t ws_size,
                              hipStream_t stream)
{
    const float* x      = (const float*)d_in[0];
    const float* inh    = (const float*)d_in[1];
    const float* branch = (const float*)d_in[2];
    const float* pwe    = (const float*)d_in[3];
    const float* pwi    = (const float*)d_in[4];
    const float* wb     = (const float*)d_in[5];
    const float* ps     = (const float*)d_in[6];
    const float* la     = (const float*)d_in[7];
    float* out = (float*)d_out;

    float2* wexc = (float2*)d_ws;
    float2* winh = (float2*)((char*)d_ws + (size_t)OUT_N * K_EXC * sizeof(float2));

    // 1024 exc waves + 1024 inh waves, 4 waves/block -> 512 blocks
    topk_both_kernel<<<(2 * OUT_N) / 4, 256, 0, stream>>>(pwe, pwi, wexc, winh);

    dendritic_main_kernel<<<B_ROWS / TILE_N, 256, 0, stream>>>(
        x, inh, (const float4*)branch, wexc, winh,
        (const float4*)wb, ps, la, out);
}